// Round 5
// baseline (292.130 us; speedup 1.0000x reference)
//
#include <hip/hip_runtime.h>

#define N_NODES 20000
#define FDIM 512
#define SSZ 6

typedef __attribute__((ext_vector_type(8))) short bf16x8;
typedef __attribute__((ext_vector_type(4))) float f32x4;
typedef __attribute__((ext_vector_type(8))) unsigned short u16x8;

static __device__ __forceinline__ unsigned short f2bf(float f) {
    unsigned int u = __float_as_uint(f);
    unsigned int r = (u + 0x7fffu + ((u >> 16) & 1u)) >> 16;
    return (unsigned short)r;
}
static __device__ __forceinline__ float bf2f(unsigned short u) {
    return __uint_as_float(((unsigned int)u) << 16);
}

// ---------------------------------------------------------------------------
// K0: fused prep. blocks [0,5000): x->bf16. blocks [5000,5512): W^T bf16.
// block 5512: zero sums. blocks [5513,5592): per-node evolution coefficients.
// ---------------------------------------------------------------------------
__global__ __launch_bounds__(256) void conv_all(
    const float* __restrict__ x, const float* __restrict__ Wre,
    const float* __restrict__ Wim, unsigned short* __restrict__ xb,
    unsigned short* __restrict__ wt, float* __restrict__ sums,
    const int* __restrict__ sub_adj, float* __restrict__ coeff)
{
    const int blk = blockIdx.x;
    const int tid = threadIdx.x;
    if (blk < 5000) {
        const size_t i = ((size_t)blk * 256 + tid) * 8;
        const float4 a = *(const float4*)(x + i);
        const float4 b = *(const float4*)(x + i + 4);
        u16x8 o;
        o[0] = f2bf(a.x); o[1] = f2bf(a.y); o[2] = f2bf(a.z); o[3] = f2bf(a.w);
        o[4] = f2bf(b.x); o[5] = f2bf(b.y); o[6] = f2bf(b.z); o[7] = f2bf(b.w);
        *(u16x8*)(xb + i) = o;
    } else if (blk < 5512) {
        __shared__ float tile[32][33];
        const int bidx = blk - 5000;
        const int z = bidx >> 8;              // 0:re 1:im
        const int rem = bidx & 255;
        const int k0 = (rem & 15) * 32;
        const int n0 = (rem >> 4) * 32;
        const float* W = z ? Wim : Wre;
        const int tx = tid & 31, ty = tid >> 5;
#pragma unroll
        for (int i = 0; i < 4; ++i)
            tile[ty + i * 8][tx] = W[(size_t)(k0 + ty + i * 8) * FDIM + n0 + tx];
        __syncthreads();
        unsigned short* wtb = wt + (size_t)z * FDIM * FDIM;
#pragma unroll
        for (int i = 0; i < 4; ++i)
            wtb[(size_t)(n0 + ty + i * 8) * FDIM + k0 + tx] = f2bf(tile[tx][ty + i * 8]);
    } else if (blk == 5512) {
#pragma unroll
        for (int i = 0; i < 8; ++i) sums[i * 256 + tid] = 0.f;
    } else {
        const int n = (blk - 5513) * 256 + tid;
        if (n >= N_NODES) return;
        const int* sa = sub_adj + (size_t)n * (SSZ * SSZ);
        float A[SSZ][SSZ], deg[SSZ];
#pragma unroll
        for (int s = 0; s < SSZ; ++s) {
            float d = 0.f;
#pragma unroll
            for (int t = 0; t < SSZ; ++t) { float a = (float)sa[s * SSZ + t]; A[s][t] = a; d += a; }
            deg[s] = d;
        }
        float p1[SSZ], p2[SSZ], p3[SSZ], p4[SSZ];
#pragma unroll
        for (int t = 0; t < SSZ; ++t) p1[t] = ((t == 0) ? deg[0] : 0.f) - A[0][t];
#pragma unroll
        for (int t = 0; t < SSZ; ++t) {
            float acc = 0.f;
#pragma unroll
            for (int s = 0; s < SSZ; ++s) acc += p1[s] * (((s == t) ? deg[s] : 0.f) - A[s][t]);
            p2[t] = acc;
        }
#pragma unroll
        for (int t = 0; t < SSZ; ++t) {
            float acc = 0.f;
#pragma unroll
            for (int s = 0; s < SSZ; ++s) acc += p2[s] * (((s == t) ? deg[s] : 0.f) - A[s][t]);
            p3[t] = acc;
        }
#pragma unroll
        for (int t = 0; t < SSZ; ++t) {
            float acc = 0.f;
#pragma unroll
            for (int s = 0; s < SSZ; ++s) acc += p3[s] * (((s == t) ? deg[s] : 0.f) - A[s][t]);
            p4[t] = acc;
        }
        float rre[SSZ], rim[SSZ];
#pragma unroll
        for (int t = 0; t < SSZ; ++t) {
            rre[t] = ((t == 0) ? 1.f : 0.f) - 3.125e-4f * p2[t] + 1.6276041666666668e-8f * p4[t];
            rim[t] = -0.025f * p1[t] + 2.6041666666666666e-6f * p3[t];
        }
        float* cf = coeff + (size_t)n * 12;
        *(float4*)(cf)     = make_float4(rre[0], rre[1], rre[2], rre[3]);
        *(float4*)(cf + 4) = make_float4(rre[4], rre[5], rim[0], rim[1]);
        *(float4*)(cf + 8) = make_float4(rim[2], rim[3], rim[4], rim[5]);
    }
}

// ---------------------------------------------------------------------------
// K1: bf16 MFMA GEMM.  y[20000][1024] = xb @ wt^T + bias (bf16 out)
// 128x128 tile, BK=64, 4 waves (2x2, wave tile 64x64), 4x4 frags 16x16x32.
// T3 minimum 2-phase double-buffer: stage(t+1) issued BEFORE compute(t),
// single end-of-tile __syncthreads (compiler vmcnt(0) drain lands after
// the MFMAs -> stage latency hides under compute).
// XCD-affinity block swizzle: 1256 = 8 x 157 exactly.
// ---------------------------------------------------------------------------
#define BM 128
#define BN 128
#define BK 64
#define NT (FDIM / BK)
#define GROWB 157   /* row panels: 20000/128 ceil */

__global__ __launch_bounds__(256) void gemm_mfma(
    const unsigned short* __restrict__ xb,   // [20000][512]
    const unsigned short* __restrict__ wt,   // [1024][512]
    const float* __restrict__ bre, const float* __restrict__ bim,
    unsigned short* __restrict__ y)          // [20000][1024]
{
    __shared__ __align__(16) unsigned short lA[2][BM * BK];   // 32 KB
    __shared__ __align__(16) unsigned short lB[2][BN * BK];   // 32 KB

    const int tid  = threadIdx.x;
    const int wave = tid >> 6;
    const int lane = tid & 63;

    // bijective XCD swizzle (nwg = 8*157, r = 0): logical = xcd*157 + slot
    const int bid     = blockIdx.x;
    const int logical = (bid & 7) * GROWB + (bid >> 3);
    const int rowBase = (logical >> 3) * BM;
    const int colBase = (logical & 7) * BN;

    const int wm = (wave >> 1) * 64;
    const int wn = (wave & 1) * 64;

    f32x4 acc[4][4];
#pragma unroll
    for (int i = 0; i < 4; ++i)
#pragma unroll
        for (int j = 0; j < 4; ++j) acc[i][j] = (f32x4){0.f, 0.f, 0.f, 0.f};

    const int srow   = lane >> 3;
    const int schunk = lane & 7;
    const int gchunk = schunk ^ srow;

    const int fm = lane & 15;
    const int kq = lane >> 4;

    // stage one BK tile into buffer buf
    auto stage = [&](int buf, int k0) {
#pragma unroll
        for (int i = 0; i < 4; ++i) {
            const int trow = wave * 32 + i * 8;
            int grow = rowBase + trow + srow;
            if (grow > N_NODES - 1) grow = N_NODES - 1;
            const unsigned short* gp = xb + (size_t)grow * FDIM + k0 + gchunk * 8;
            __builtin_amdgcn_global_load_lds(
                (const __attribute__((address_space(1))) void*)gp,
                (__attribute__((address_space(3))) void*)(&lA[buf][trow * BK]), 16, 0, 0);
        }
#pragma unroll
        for (int i = 0; i < 4; ++i) {
            const int trow = wave * 32 + i * 8;
            const int grow = colBase + trow + srow;
            const unsigned short* gp = wt + (size_t)grow * FDIM + k0 + gchunk * 8;
            __builtin_amdgcn_global_load_lds(
                (const __attribute__((address_space(1))) void*)gp,
                (__attribute__((address_space(3))) void*)(&lB[buf][trow * BK]), 16, 0, 0);
        }
    };

    // prologue: fill buffer 0, drain, join
    stage(0, 0);
    __syncthreads();

#pragma unroll
    for (int t = 0; t < NT; ++t) {
        const int cur = t & 1;
        if (t + 1 < NT) stage(cur ^ 1, (t + 1) * BK);   // issue next tile first

        const unsigned short* pA = lA[cur];
        const unsigned short* pB = lB[cur];
#pragma unroll
        for (int ks = 0; ks < 2; ++ks) {
            bf16x8 af[4], bfr[4];
            const int g = ks * 4 + kq;
#pragma unroll
            for (int mt = 0; mt < 4; ++mt) {
                const int row = wm + mt * 16 + fm;
                af[mt] = *(const bf16x8*)&pA[row * BK + ((g ^ (row & 7)) << 3)];
            }
#pragma unroll
            for (int nt = 0; nt < 4; ++nt) {
                const int row = wn + nt * 16 + fm;
                bfr[nt] = *(const bf16x8*)&pB[row * BK + ((g ^ (row & 7)) << 3)];
            }
#pragma unroll
            for (int mt = 0; mt < 4; ++mt)
#pragma unroll
                for (int nt = 0; nt < 4; ++nt)
                    acc[mt][nt] = __builtin_amdgcn_mfma_f32_16x16x32_bf16(
                        af[mt], bfr[nt], acc[mt][nt], 0, 0, 0);
        }
        // drain (vmcnt for stage(t+1), lgkm for ds_reads) + join, once per tile
        __syncthreads();
    }

    const int rquad = lane >> 4;
#pragma unroll
    for (int nt = 0; nt < 4; ++nt) {
        const int col = colBase + wn + nt * 16 + fm;
        const float bias = (col < FDIM) ? bre[col] : bim[col - FDIM];
#pragma unroll
        for (int mt = 0; mt < 4; ++mt) {
            const int row0 = rowBase + wm + mt * 16 + rquad * 4;
#pragma unroll
            for (int r = 0; r < 4; ++r) {
                const int row = row0 + r;
                if (row < N_NODES)
                    y[(size_t)row * 1024 + col] = f2bf(acc[mt][nt][r] + bias);
            }
        }
    }
}

// ---------------------------------------------------------------------------
// K2: pure evolve + ReLU -> eb. No LDS, no atomics, no syncthreads.
// Block = 8 nodes (4 waves x 2 nodes).
// ---------------------------------------------------------------------------
__global__ __launch_bounds__(256) void evolve_kernel(
    const unsigned short* __restrict__ y,
    const int* __restrict__ sub_nodes,
    const float* __restrict__ coeff,
    unsigned short* __restrict__ eb)
{
    const int wave = threadIdx.x >> 6;
    const int lane = threadIdx.x & 63;
    const int f = lane << 3;

#pragma unroll 1
    for (int q = 0; q < 2; ++q) {
        const int n = blockIdx.x * 8 + wave * 2 + q;

        // wave-uniform coefficient load (L1 broadcast)
        const float* cf = coeff + (size_t)n * 12;
        const float4 c0 = *(const float4*)(cf);
        const float4 c1 = *(const float4*)(cf + 4);
        const float4 c2 = *(const float4*)(cf + 8);
        const float rre[SSZ] = {c0.x, c0.y, c0.z, c0.w, c1.x, c1.y};
        const float rim[SSZ] = {c1.z, c1.w, c2.x, c2.y, c2.z, c2.w};

        // gather + complex combine
        float aR[8] = {0.f}, aI[8] = {0.f};
#pragma unroll
        for (int s = 0; s < SSZ; ++s) {
            const int nd = sub_nodes[n * SSZ + s];
            const float cr = rre[s], ci = rim[s];
            const unsigned short* base = y + (size_t)nd * 1024 + f;
            const u16x8 yr8 = *(const u16x8*)base;
            const u16x8 yi8 = *(const u16x8*)(base + FDIM);
#pragma unroll
            for (int j = 0; j < 8; ++j) {
                const float yr = bf2f(yr8[j]);
                const float yi = bf2f(yi8[j]);
                aR[j] = fmaf(cr, yr, fmaf(-ci, yi, aR[j]));
                aI[j] = fmaf(cr, yi, fmaf(ci, yr, aI[j]));
            }
        }
        u16x8 er8, ei8;
#pragma unroll
        for (int j = 0; j < 8; ++j) {
            er8[j] = f2bf(fmaxf(aR[j], 0.f));
            ei8[j] = f2bf(fmaxf(aI[j], 0.f));
        }
        *(u16x8*)(eb + (size_t)n * 1024 + f) = er8;
        *(u16x8*)(eb + (size_t)n * 1024 + FDIM + f) = ei8;
    }
}

// ---------------------------------------------------------------------------
// K2b: BN stats over eb. 200 blocks x 100 rows. Thread = 8 cols, 2-row
// interleave. LDS pair-combine -> 2048 atomics/block (410K total).
// ---------------------------------------------------------------------------
#define SROWS 100

__global__ __launch_bounds__(256) void stats_kernel(
    const unsigned short* __restrict__ eb, float* __restrict__ sums)
{
    __shared__ float ls[2][1024], ls2[2][1024];   // 16 KB
    const int tid  = threadIdx.x;
    const int colg = tid & 127;
    const int rh   = tid >> 7;
    const int c    = colg << 3;

    float s[8] = {0.f}, s2[8] = {0.f};
    const int r0 = blockIdx.x * SROWS;
#pragma unroll 2
    for (int r = r0 + rh; r < r0 + SROWS; r += 2) {
        const u16x8 v = *(const u16x8*)(eb + (size_t)r * 1024 + c);
#pragma unroll
        for (int j = 0; j < 8; ++j) {
            const float xv = bf2f(v[j]);
            s[j] += xv;
            s2[j] = fmaf(xv, xv, s2[j]);
        }
    }
#pragma unroll
    for (int j = 0; j < 8; ++j) { ls[rh][c + j] = s[j]; ls2[rh][c + j] = s2[j]; }
    __syncthreads();
    if (rh == 0) {
#pragma unroll
        for (int j = 0; j < 8; ++j) {
            const float a = s[j] + ls[1][c + j];
            const float b = s2[j] + ls2[1][c + j];
            const int cc = c + j;
            if (cc < 512) {
                atomicAdd(&sums[cc], a);
                atomicAdd(&sums[cc + 512], b);
            } else {
                atomicAdd(&sums[cc + 512], a);
                atomicAdd(&sums[cc + 1024], b);
            }
        }
    }
}

// ---------------------------------------------------------------------------
// K3: finalize. Per-thread BN params from sums (register, float4 loads),
// apply + residual, write fp32 out.
// ---------------------------------------------------------------------------
__global__ __launch_bounds__(256) void finalize_kernel(
    const float* __restrict__ x, const unsigned short* __restrict__ eb,
    const float* __restrict__ sums,
    const float* __restrict__ gr, const float* __restrict__ br_,
    const float* __restrict__ gi, const float* __restrict__ bi_,
    float* __restrict__ out)
{
    const int gid = blockIdx.x * 256 + threadIdx.x;    // N*64 threads
    const int n = gid >> 6;
    const int f = (gid & 63) << 3;
    const float invN = 1.0f / (float)N_NODES;

    float scr[8], shr[8], sci[8], shi[8];
#pragma unroll
    for (int h = 0; h < 2; ++h) {
        const int fo = f + h * 4;
        const float4 s1 = *(const float4*)(sums + fo);
        const float4 s2 = *(const float4*)(sums + 512 + fo);
        const float4 s3 = *(const float4*)(sums + 1024 + fo);
        const float4 s4 = *(const float4*)(sums + 1536 + fo);
        const float4 g1 = *(const float4*)(gr + fo);
        const float4 b1 = *(const float4*)(br_ + fo);
        const float4 g2 = *(const float4*)(gi + fo);
        const float4 b2 = *(const float4*)(bi_ + fo);
        const float mu[4] = {s1.x * invN, s1.y * invN, s1.z * invN, s1.w * invN};
        const float q2[4] = {s2.x * invN, s2.y * invN, s2.z * invN, s2.w * invN};
        const float mi[4] = {s3.x * invN, s3.y * invN, s3.z * invN, s3.w * invN};
        const float qi[4] = {s4.x * invN, s4.y * invN, s4.z * invN, s4.w * invN};
        const float gg1[4] = {g1.x, g1.y, g1.z, g1.w};
        const float bb1[4] = {b1.x, b1.y, b1.z, b1.w};
        const float gg2[4] = {g2.x, g2.y, g2.z, g2.w};
        const float bb2[4] = {b2.x, b2.y, b2.z, b2.w};
#pragma unroll
        for (int j = 0; j < 4; ++j) {
            const float vr = fmaf(-mu[j], mu[j], q2[j]);
            const float sc1 = rsqrtf(vr + 1e-5f) * gg1[j];
            scr[h * 4 + j] = sc1;
            shr[h * 4 + j] = fmaf(-mu[j], sc1, bb1[j]);
            const float vi = fmaf(-mi[j], mi[j], qi[j]);
            const float sc2 = rsqrtf(vi + 1e-5f) * gg2[j];
            sci[h * 4 + j] = sc2;
            shi[h * 4 + j] = fmaf(-mi[j], sc2, bb2[j]);
        }
    }

    const u16x8 er8 = *(const u16x8*)(eb + (size_t)n * 1024 + f);
    const u16x8 ei8 = *(const u16x8*)(eb + (size_t)n * 1024 + FDIM + f);
    float orr[8], oii[8];
#pragma unroll
    for (int j = 0; j < 8; ++j) {
        const float xv = x[(size_t)n * FDIM + f + j];
        orr[j] = fmaf(bf2f(er8[j]), scr[j], shr[j]) + xv;
        oii[j] = fmaf(bf2f(ei8[j]), sci[j], shi[j]);
    }
#pragma unroll
    for (int j = 0; j < 8; j += 4) {
        *(float4*)(out + (size_t)n * 1024 + f + j) =
            make_float4(orr[j], orr[j + 1], orr[j + 2], orr[j + 3]);
        *(float4*)(out + (size_t)n * 1024 + FDIM + f + j) =
            make_float4(oii[j], oii[j + 1], oii[j + 2], oii[j + 3]);
    }
}

extern "C" void kernel_launch(void* const* d_in, const int* in_sizes, int n_in,
                              void* d_out, int out_size, void* d_ws, size_t ws_size,
                              hipStream_t stream)
{
    const float* x        = (const float*)d_in[0];
    const int* sub_nodes  = (const int*)d_in[2];
    const int* sub_adj    = (const int*)d_in[3];
    const float* Wre      = (const float*)d_in[4];
    const float* Wim      = (const float*)d_in[5];
    const float* bre      = (const float*)d_in[6];
    const float* bim      = (const float*)d_in[7];
    const float* gr       = (const float*)d_in[8];
    const float* br_      = (const float*)d_in[9];
    const float* gi       = (const float*)d_in[10];
    const float* bi_      = (const float*)d_in[11];
    float* out = (float*)d_out;

    unsigned short* y  = (unsigned short*)d_ws;                     // N*1024 bf16
    unsigned short* eb = y + (size_t)N_NODES * 1024;                // N*1024 bf16
    unsigned short* xb = eb + (size_t)N_NODES * 1024;               // N*512  bf16
    unsigned short* wt = xb + (size_t)N_NODES * FDIM;               // 1024*512 bf16
    float* sums        = (float*)(wt + (size_t)1024 * FDIM);        // 2048
    float* coeff       = sums + 2048;                               // N*12 = 960 KB

    conv_all<<<5513 + 79, 256, 0, stream>>>(x, Wre, Wim, xb, wt, sums, sub_adj, coeff);

    gemm_mfma<<<8 * GROWB, 256, 0, stream>>>(xb, wt, bre, bim, y);

    evolve_kernel<<<N_NODES / 8, 256, 0, stream>>>(y, sub_nodes, coeff, eb);

    stats_kernel<<<N_NODES / SROWS, 256, 0, stream>>>(eb, sums);

    finalize_kernel<<<(N_NODES * 64) / 256, 256, 0, stream>>>(
        x, eb, sums, gr, br_, gi, bi_, out);
}

// Round 6
// 282.374 us; speedup vs baseline: 1.0345x; 1.0345x over previous
//
#include <hip/hip_runtime.h>

#define N_NODES 20000
#define FDIM 512
#define SSZ 6

typedef __attribute__((ext_vector_type(8))) short bf16x8;
typedef __attribute__((ext_vector_type(4))) float f32x4;
typedef __attribute__((ext_vector_type(8))) unsigned short u16x8;

static __device__ __forceinline__ unsigned short f2bf(float f) {
    unsigned int u = __float_as_uint(f);
    unsigned int r = (u + 0x7fffu + ((u >> 16) & 1u)) >> 16;
    return (unsigned short)r;
}
static __device__ __forceinline__ float bf2f(unsigned short u) {
    return __uint_as_float(((unsigned int)u) << 16);
}

// ---------------------------------------------------------------------------
// K0: fused prep. blocks [0,5000): x->bf16. blocks [5000,5512): W^T bf16.
// block 5512: zero sums. blocks [5513,5592): per-node evolution coefficients.
// ---------------------------------------------------------------------------
__global__ __launch_bounds__(256) void conv_all(
    const float* __restrict__ x, const float* __restrict__ Wre,
    const float* __restrict__ Wim, unsigned short* __restrict__ xb,
    unsigned short* __restrict__ wt, float* __restrict__ sums,
    const int* __restrict__ sub_adj, float* __restrict__ coeff)
{
    const int blk = blockIdx.x;
    const int tid = threadIdx.x;
    if (blk < 5000) {
        const size_t i = ((size_t)blk * 256 + tid) * 8;
        const float4 a = *(const float4*)(x + i);
        const float4 b = *(const float4*)(x + i + 4);
        u16x8 o;
        o[0] = f2bf(a.x); o[1] = f2bf(a.y); o[2] = f2bf(a.z); o[3] = f2bf(a.w);
        o[4] = f2bf(b.x); o[5] = f2bf(b.y); o[6] = f2bf(b.z); o[7] = f2bf(b.w);
        *(u16x8*)(xb + i) = o;
    } else if (blk < 5512) {
        __shared__ float tile[32][33];
        const int bidx = blk - 5000;
        const int z = bidx >> 8;              // 0:re 1:im
        const int rem = bidx & 255;
        const int k0 = (rem & 15) * 32;
        const int n0 = (rem >> 4) * 32;
        const float* W = z ? Wim : Wre;
        const int tx = tid & 31, ty = tid >> 5;
#pragma unroll
        for (int i = 0; i < 4; ++i)
            tile[ty + i * 8][tx] = W[(size_t)(k0 + ty + i * 8) * FDIM + n0 + tx];
        __syncthreads();
        unsigned short* wtb = wt + (size_t)z * FDIM * FDIM;
#pragma unroll
        for (int i = 0; i < 4; ++i)
            wtb[(size_t)(n0 + ty + i * 8) * FDIM + k0 + tx] = f2bf(tile[tx][ty + i * 8]);
    } else if (blk == 5512) {
#pragma unroll
        for (int i = 0; i < 8; ++i) sums[i * 256 + tid] = 0.f;
    } else {
        const int n = (blk - 5513) * 256 + tid;
        if (n >= N_NODES) return;
        const int* sa = sub_adj + (size_t)n * (SSZ * SSZ);
        float A[SSZ][SSZ], deg[SSZ];
#pragma unroll
        for (int s = 0; s < SSZ; ++s) {
            float d = 0.f;
#pragma unroll
            for (int t = 0; t < SSZ; ++t) { float a = (float)sa[s * SSZ + t]; A[s][t] = a; d += a; }
            deg[s] = d;
        }
        float p1[SSZ], p2[SSZ], p3[SSZ], p4[SSZ];
#pragma unroll
        for (int t = 0; t < SSZ; ++t) p1[t] = ((t == 0) ? deg[0] : 0.f) - A[0][t];
#pragma unroll
        for (int t = 0; t < SSZ; ++t) {
            float acc = 0.f;
#pragma unroll
            for (int s = 0; s < SSZ; ++s) acc += p1[s] * (((s == t) ? deg[s] : 0.f) - A[s][t]);
            p2[t] = acc;
        }
#pragma unroll
        for (int t = 0; t < SSZ; ++t) {
            float acc = 0.f;
#pragma unroll
            for (int s = 0; s < SSZ; ++s) acc += p2[s] * (((s == t) ? deg[s] : 0.f) - A[s][t]);
            p3[t] = acc;
        }
#pragma unroll
        for (int t = 0; t < SSZ; ++t) {
            float acc = 0.f;
#pragma unroll
            for (int s = 0; s < SSZ; ++s) acc += p3[s] * (((s == t) ? deg[s] : 0.f) - A[s][t]);
            p4[t] = acc;
        }
        float rre[SSZ], rim[SSZ];
#pragma unroll
        for (int t = 0; t < SSZ; ++t) {
            rre[t] = ((t == 0) ? 1.f : 0.f) - 3.125e-4f * p2[t] + 1.6276041666666668e-8f * p4[t];
            rim[t] = -0.025f * p1[t] + 2.6041666666666666e-6f * p3[t];
        }
        float* cf = coeff + (size_t)n * 12;
        *(float4*)(cf)     = make_float4(rre[0], rre[1], rre[2], rre[3]);
        *(float4*)(cf + 4) = make_float4(rre[4], rre[5], rim[0], rim[1]);
        *(float4*)(cf + 8) = make_float4(rim[2], rim[3], rim[4], rim[5]);
    }
}

// ---------------------------------------------------------------------------
// K1: bf16 MFMA GEMM.  y[20000][1024] = xb @ wt^T + bias (bf16 out)
// 64x128 tile (the ~22 us R1 structure: 2512 blocks, 24 KB LDS, ~6 blk/CU
// TLP wins in this skinny latency-bound shape), BK=64, 4 waves (2x2,
// wave tile 32x64), 2x4 frags 16x16x32. global_load_lds w=16, XOR swizzle.
// + XCD-affinity block swizzle: 2504 = 8 x 313 exactly (bijective, q=313)
// to kill the 81 MB A-panel refetch seen in R3.
// ---------------------------------------------------------------------------
#define BM 64
#define BN 128
#define BK 64
#define GROWB 313   /* row panels: ceil(20000/64) */

__global__ __launch_bounds__(256) void gemm_mfma(
    const unsigned short* __restrict__ xb,   // [20000][512]
    const unsigned short* __restrict__ wt,   // [1024][512]
    const float* __restrict__ bre, const float* __restrict__ bim,
    unsigned short* __restrict__ y)          // [20000][1024]
{
    __shared__ __align__(16) unsigned short lA[BM * BK];   // 8 KB
    __shared__ __align__(16) unsigned short lB[BN * BK];   // 16 KB

    const int tid  = threadIdx.x;
    const int wave = tid >> 6;
    const int lane = tid & 63;

    // bijective XCD swizzle (nwg = 8*313, r = 0): logical = xcd*313 + slot
    const int bid     = blockIdx.x;
    const int logical = (bid & 7) * GROWB + (bid >> 3);
    const int rowBase = (logical >> 3) * BM;
    const int colBase = (logical & 7) * BN;

    const int wm = (wave >> 1) * 32;
    const int wn = (wave & 1) * 64;

    f32x4 acc[2][4];
#pragma unroll
    for (int i = 0; i < 2; ++i)
#pragma unroll
        for (int j = 0; j < 4; ++j) acc[i][j] = (f32x4){0.f, 0.f, 0.f, 0.f};

    const int srow   = lane >> 3;
    const int schunk = lane & 7;
    const int gchunk = schunk ^ srow;

    const int fm = lane & 15;
    const int kq = lane >> 4;

    for (int k0 = 0; k0 < FDIM; k0 += BK) {
        // stage A: wave stages rows [wave*16, wave*16+16)
#pragma unroll
        for (int i = 0; i < 2; ++i) {
            const int trow = wave * 16 + i * 8;
            int grow = rowBase + trow + srow;
            if (grow > N_NODES - 1) grow = N_NODES - 1;
            const unsigned short* gp = xb + (size_t)grow * FDIM + k0 + gchunk * 8;
            __builtin_amdgcn_global_load_lds(
                (const __attribute__((address_space(1))) void*)gp,
                (__attribute__((address_space(3))) void*)(lA + trow * BK), 16, 0, 0);
        }
        // stage B: wave stages rows [wave*32, wave*32+32)
#pragma unroll
        for (int i = 0; i < 4; ++i) {
            const int trow = wave * 32 + i * 8;
            const int grow = colBase + trow + srow;
            const unsigned short* gp = wt + (size_t)grow * FDIM + k0 + gchunk * 8;
            __builtin_amdgcn_global_load_lds(
                (const __attribute__((address_space(1))) void*)gp,
                (__attribute__((address_space(3))) void*)(lB + trow * BK), 16, 0, 0);
        }
        __syncthreads();

#pragma unroll
        for (int ks = 0; ks < 2; ++ks) {
            bf16x8 af[2], bfr[4];
            const int g = ks * 4 + kq;
#pragma unroll
            for (int mt = 0; mt < 2; ++mt) {
                const int row = wm + mt * 16 + fm;
                af[mt] = *(const bf16x8*)&lA[row * BK + ((g ^ (row & 7)) << 3)];
            }
#pragma unroll
            for (int nt = 0; nt < 4; ++nt) {
                const int row = wn + nt * 16 + fm;
                bfr[nt] = *(const bf16x8*)&lB[row * BK + ((g ^ (row & 7)) << 3)];
            }
#pragma unroll
            for (int mt = 0; mt < 2; ++mt)
#pragma unroll
                for (int nt = 0; nt < 4; ++nt)
                    acc[mt][nt] = __builtin_amdgcn_mfma_f32_16x16x32_bf16(
                        af[mt], bfr[nt], acc[mt][nt], 0, 0, 0);
        }
        __syncthreads();
    }

    const int rquad = lane >> 4;
#pragma unroll
    for (int nt = 0; nt < 4; ++nt) {
        const int col = colBase + wn + nt * 16 + fm;
        const float bias = (col < FDIM) ? bre[col] : bim[col - FDIM];
#pragma unroll
        for (int mt = 0; mt < 2; ++mt) {
            const int row0 = rowBase + wm + mt * 16 + rquad * 4;
#pragma unroll
            for (int r = 0; r < 4; ++r) {
                const int row = row0 + r;
                if (row < N_NODES)
                    y[(size_t)row * 1024 + col] = f2bf(acc[mt][nt][r] + bias);
            }
        }
    }
}

// ---------------------------------------------------------------------------
// K2: pure evolve + ReLU -> eb. No LDS, no atomics, no syncthreads.
// Block = 8 nodes (4 waves x 2 nodes).
// ---------------------------------------------------------------------------
__global__ __launch_bounds__(256) void evolve_kernel(
    const unsigned short* __restrict__ y,
    const int* __restrict__ sub_nodes,
    const float* __restrict__ coeff,
    unsigned short* __restrict__ eb)
{
    const int wave = threadIdx.x >> 6;
    const int lane = threadIdx.x & 63;
    const int f = lane << 3;

#pragma unroll 1
    for (int q = 0; q < 2; ++q) {
        const int n = blockIdx.x * 8 + wave * 2 + q;

        // wave-uniform coefficient load (L1 broadcast)
        const float* cf = coeff + (size_t)n * 12;
        const float4 c0 = *(const float4*)(cf);
        const float4 c1 = *(const float4*)(cf + 4);
        const float4 c2 = *(const float4*)(cf + 8);
        const float rre[SSZ] = {c0.x, c0.y, c0.z, c0.w, c1.x, c1.y};
        const float rim[SSZ] = {c1.z, c1.w, c2.x, c2.y, c2.z, c2.w};

        // gather + complex combine
        float aR[8] = {0.f}, aI[8] = {0.f};
#pragma unroll
        for (int s = 0; s < SSZ; ++s) {
            const int nd = sub_nodes[n * SSZ + s];
            const float cr = rre[s], ci = rim[s];
            const unsigned short* base = y + (size_t)nd * 1024 + f;
            const u16x8 yr8 = *(const u16x8*)base;
            const u16x8 yi8 = *(const u16x8*)(base + FDIM);
#pragma unroll
            for (int j = 0; j < 8; ++j) {
                const float yr = bf2f(yr8[j]);
                const float yi = bf2f(yi8[j]);
                aR[j] = fmaf(cr, yr, fmaf(-ci, yi, aR[j]));
                aI[j] = fmaf(cr, yi, fmaf(ci, yr, aI[j]));
            }
        }
        u16x8 er8, ei8;
#pragma unroll
        for (int j = 0; j < 8; ++j) {
            er8[j] = f2bf(fmaxf(aR[j], 0.f));
            ei8[j] = f2bf(fmaxf(aI[j], 0.f));
        }
        *(u16x8*)(eb + (size_t)n * 1024 + f) = er8;
        *(u16x8*)(eb + (size_t)n * 1024 + FDIM + f) = ei8;
    }
}

// ---------------------------------------------------------------------------
// K2b: BN stats over eb. 200 blocks x 100 rows. Thread = 8 cols, 2-row
// interleave. LDS pair-combine -> 2048 atomics/block (410K total).
// ---------------------------------------------------------------------------
#define SROWS 100

__global__ __launch_bounds__(256) void stats_kernel(
    const unsigned short* __restrict__ eb, float* __restrict__ sums)
{
    __shared__ float ls[2][1024], ls2[2][1024];   // 16 KB
    const int tid  = threadIdx.x;
    const int colg = tid & 127;
    const int rh   = tid >> 7;
    const int c    = colg << 3;

    float s[8] = {0.f}, s2[8] = {0.f};
    const int r0 = blockIdx.x * SROWS;
#pragma unroll 2
    for (int r = r0 + rh; r < r0 + SROWS; r += 2) {
        const u16x8 v = *(const u16x8*)(eb + (size_t)r * 1024 + c);
#pragma unroll
        for (int j = 0; j < 8; ++j) {
            const float xv = bf2f(v[j]);
            s[j] += xv;
            s2[j] = fmaf(xv, xv, s2[j]);
        }
    }
#pragma unroll
    for (int j = 0; j < 8; ++j) { ls[rh][c + j] = s[j]; ls2[rh][c + j] = s2[j]; }
    __syncthreads();
    if (rh == 0) {
#pragma unroll
        for (int j = 0; j < 8; ++j) {
            const float a = s[j] + ls[1][c + j];
            const float b = s2[j] + ls2[1][c + j];
            const int cc = c + j;
            if (cc < 512) {
                atomicAdd(&sums[cc], a);
                atomicAdd(&sums[cc + 512], b);
            } else {
                atomicAdd(&sums[cc + 512], a);
                atomicAdd(&sums[cc + 1024], b);
            }
        }
    }
}

// ---------------------------------------------------------------------------
// K3: finalize. Per-thread BN params from sums (register, float4 loads),
// apply + residual, write fp32 out.
// ---------------------------------------------------------------------------
__global__ __launch_bounds__(256) void finalize_kernel(
    const float* __restrict__ x, const unsigned short* __restrict__ eb,
    const float* __restrict__ sums,
    const float* __restrict__ gr, const float* __restrict__ br_,
    const float* __restrict__ gi, const float* __restrict__ bi_,
    float* __restrict__ out)
{
    const int gid = blockIdx.x * 256 + threadIdx.x;    // N*64 threads
    const int n = gid >> 6;
    const int f = (gid & 63) << 3;
    const float invN = 1.0f / (float)N_NODES;

    float scr[8], shr[8], sci[8], shi[8];
#pragma unroll
    for (int h = 0; h < 2; ++h) {
        const int fo = f + h * 4;
        const float4 s1 = *(const float4*)(sums + fo);
        const float4 s2 = *(const float4*)(sums + 512 + fo);
        const float4 s3 = *(const float4*)(sums + 1024 + fo);
        const float4 s4 = *(const float4*)(sums + 1536 + fo);
        const float4 g1 = *(const float4*)(gr + fo);
        const float4 b1 = *(const float4*)(br_ + fo);
        const float4 g2 = *(const float4*)(gi + fo);
        const float4 b2 = *(const float4*)(bi_ + fo);
        const float mu[4] = {s1.x * invN, s1.y * invN, s1.z * invN, s1.w * invN};
        const float q2[4] = {s2.x * invN, s2.y * invN, s2.z * invN, s2.w * invN};
        const float mi[4] = {s3.x * invN, s3.y * invN, s3.z * invN, s3.w * invN};
        const float qi[4] = {s4.x * invN, s4.y * invN, s4.z * invN, s4.w * invN};
        const float gg1[4] = {g1.x, g1.y, g1.z, g1.w};
        const float bb1[4] = {b1.x, b1.y, b1.z, b1.w};
        const float gg2[4] = {g2.x, g2.y, g2.z, g2.w};
        const float bb2[4] = {b2.x, b2.y, b2.z, b2.w};
#pragma unroll
        for (int j = 0; j < 4; ++j) {
            const float vr = fmaf(-mu[j], mu[j], q2[j]);
            const float sc1 = rsqrtf(vr + 1e-5f) * gg1[j];
            scr[h * 4 + j] = sc1;
            shr[h * 4 + j] = fmaf(-mu[j], sc1, bb1[j]);
            const float vi = fmaf(-mi[j], mi[j], qi[j]);
            const float sc2 = rsqrtf(vi + 1e-5f) * gg2[j];
            sci[h * 4 + j] = sc2;
            shi[h * 4 + j] = fmaf(-mi[j], sc2, bb2[j]);
        }
    }

    const u16x8 er8 = *(const u16x8*)(eb + (size_t)n * 1024 + f);
    const u16x8 ei8 = *(const u16x8*)(eb + (size_t)n * 1024 + FDIM + f);
    float orr[8], oii[8];
#pragma unroll
    for (int j = 0; j < 8; ++j) {
        const float xv = x[(size_t)n * FDIM + f + j];
        orr[j] = fmaf(bf2f(er8[j]), scr[j], shr[j]) + xv;
        oii[j] = fmaf(bf2f(ei8[j]), sci[j], shi[j]);
    }
#pragma unroll
    for (int j = 0; j < 8; j += 4) {
        *(float4*)(out + (size_t)n * 1024 + f + j) =
            make_float4(orr[j], orr[j + 1], orr[j + 2], orr[j + 3]);
        *(float4*)(out + (size_t)n * 1024 + FDIM + f + j) =
            make_float4(oii[j], oii[j + 1], oii[j + 2], oii[j + 3]);
    }
}

extern "C" void kernel_launch(void* const* d_in, const int* in_sizes, int n_in,
                              void* d_out, int out_size, void* d_ws, size_t ws_size,
                              hipStream_t stream)
{
    const float* x        = (const float*)d_in[0];
    const int* sub_nodes  = (const int*)d_in[2];
    const int* sub_adj    = (const int*)d_in[3];
    const float* Wre      = (const float*)d_in[4];
    const float* Wim      = (const float*)d_in[5];
    const float* bre      = (const float*)d_in[6];
    const float* bim      = (const float*)d_in[7];
    const float* gr       = (const float*)d_in[8];
    const float* br_      = (const float*)d_in[9];
    const float* gi       = (const float*)d_in[10];
    const float* bi_      = (const float*)d_in[11];
    float* out = (float*)d_out;

    unsigned short* y  = (unsigned short*)d_ws;                     // N*1024 bf16
    unsigned short* eb = y + (size_t)N_NODES * 1024;                // N*1024 bf16
    unsigned short* xb = eb + (size_t)N_NODES * 1024;               // N*512  bf16
    unsigned short* wt = xb + (size_t)N_NODES * FDIM;               // 1024*512 bf16
    float* sums        = (float*)(wt + (size_t)1024 * FDIM);        // 2048
    float* coeff       = sums + 2048;                               // N*12 = 960 KB

    conv_all<<<5513 + 79, 256, 0, stream>>>(x, Wre, Wim, xb, wt, sums, sub_adj, coeff);

    gemm_mfma<<<8 * GROWB, 256, 0, stream>>>(xb, wt, bre, bim, y);

    evolve_kernel<<<N_NODES / 8, 256, 0, stream>>>(y, sub_nodes, coeff, eb);

    stats_kernel<<<N_NODES / SROWS, 256, 0, stream>>>(eb, sums);

    finalize_kernel<<<(N_NODES * 64) / 256, 256, 0, stream>>>(
        x, eb, sums, gr, br_, gi, bi_, out);
}

// Round 9
// 263.062 us; speedup vs baseline: 1.1105x; 1.0734x over previous
//
#include <hip/hip_runtime.h>

#define N_NODES 20000
#define FDIM 512
#define SSZ 6

typedef __attribute__((ext_vector_type(8))) short bf16x8;
typedef __attribute__((ext_vector_type(4))) float f32x4;
typedef __attribute__((ext_vector_type(8))) unsigned short u16x8;

static __device__ __forceinline__ unsigned short f2bf(float f) {
    unsigned int u = __float_as_uint(f);
    unsigned int r = (u + 0x7fffu + ((u >> 16) & 1u)) >> 16;
    return (unsigned short)r;
}
static __device__ __forceinline__ float bf2f(unsigned short u) {
    return __uint_as_float(((unsigned int)u) << 16);
}

// ---------------------------------------------------------------------------
// K0: fused prep. blocks [0,5000): x->bf16. blocks [5000,5512): W^T bf16.
// block 5512: zero sums. blocks [5513,5592): per-node evolution coefficients.
// ---------------------------------------------------------------------------
__global__ __launch_bounds__(256) void conv_all(
    const float* __restrict__ x, const float* __restrict__ Wre,
    const float* __restrict__ Wim, unsigned short* __restrict__ xb,
    unsigned short* __restrict__ wt, float* __restrict__ sums,
    const int* __restrict__ sub_adj, float* __restrict__ coeff)
{
    const int blk = blockIdx.x;
    const int tid = threadIdx.x;
    if (blk < 5000) {
        const size_t i = ((size_t)blk * 256 + tid) * 8;
        const float4 a = *(const float4*)(x + i);
        const float4 b = *(const float4*)(x + i + 4);
        u16x8 o;
        o[0] = f2bf(a.x); o[1] = f2bf(a.y); o[2] = f2bf(a.z); o[3] = f2bf(a.w);
        o[4] = f2bf(b.x); o[5] = f2bf(b.y); o[6] = f2bf(b.z); o[7] = f2bf(b.w);
        *(u16x8*)(xb + i) = o;
    } else if (blk < 5512) {
        __shared__ float tile[32][33];
        const int bidx = blk - 5000;
        const int z = bidx >> 8;              // 0:re 1:im
        const int rem = bidx & 255;
        const int k0 = (rem & 15) * 32;
        const int n0 = (rem >> 4) * 32;
        const float* W = z ? Wim : Wre;
        const int tx = tid & 31, ty = tid >> 5;
#pragma unroll
        for (int i = 0; i < 4; ++i)
            tile[ty + i * 8][tx] = W[(size_t)(k0 + ty + i * 8) * FDIM + n0 + tx];
        __syncthreads();
        unsigned short* wtb = wt + (size_t)z * FDIM * FDIM;
#pragma unroll
        for (int i = 0; i < 4; ++i)
            wtb[(size_t)(n0 + ty + i * 8) * FDIM + k0 + tx] = f2bf(tile[tx][ty + i * 8]);
    } else if (blk == 5512) {
#pragma unroll
        for (int i = 0; i < 8; ++i) sums[i * 256 + tid] = 0.f;
    } else {
        const int n = (blk - 5513) * 256 + tid;
        if (n >= N_NODES) return;
        const int* sa = sub_adj + (size_t)n * (SSZ * SSZ);
        float A[SSZ][SSZ], deg[SSZ];
#pragma unroll
        for (int s = 0; s < SSZ; ++s) {
            float d = 0.f;
#pragma unroll
            for (int t = 0; t < SSZ; ++t) { float a = (float)sa[s * SSZ + t]; A[s][t] = a; d += a; }
            deg[s] = d;
        }
        float p1[SSZ], p2[SSZ], p3[SSZ], p4[SSZ];
#pragma unroll
        for (int t = 0; t < SSZ; ++t) p1[t] = ((t == 0) ? deg[0] : 0.f) - A[0][t];
#pragma unroll
        for (int t = 0; t < SSZ; ++t) {
            float acc = 0.f;
#pragma unroll
            for (int s = 0; s < SSZ; ++s) acc += p1[s] * (((s == t) ? deg[s] : 0.f) - A[s][t]);
            p2[t] = acc;
        }
#pragma unroll
        for (int t = 0; t < SSZ; ++t) {
            float acc = 0.f;
#pragma unroll
            for (int s = 0; s < SSZ; ++s) acc += p2[s] * (((s == t) ? deg[s] : 0.f) - A[s][t]);
            p3[t] = acc;
        }
#pragma unroll
        for (int t = 0; t < SSZ; ++t) {
            float acc = 0.f;
#pragma unroll
            for (int s = 0; s < SSZ; ++s) acc += p3[s] * (((s == t) ? deg[s] : 0.f) - A[s][t]);
            p4[t] = acc;
        }
        float rre[SSZ], rim[SSZ];
#pragma unroll
        for (int t = 0; t < SSZ; ++t) {
            rre[t] = ((t == 0) ? 1.f : 0.f) - 3.125e-4f * p2[t] + 1.6276041666666668e-8f * p4[t];
            rim[t] = -0.025f * p1[t] + 2.6041666666666666e-6f * p3[t];
        }
        float* cf = coeff + (size_t)n * 12;
        *(float4*)(cf)     = make_float4(rre[0], rre[1], rre[2], rre[3]);
        *(float4*)(cf + 4) = make_float4(rre[4], rre[5], rim[0], rim[1]);
        *(float4*)(cf + 8) = make_float4(rim[2], rim[3], rim[4], rim[5]);
    }
}

// ---------------------------------------------------------------------------
// K1: bf16 MFMA GEMM.  y[20000][1024] = xb @ wt^T + bias (bf16 out)
// 64x128 tile, BK=64, 4 waves (2x2, wave tile 32x64), 2x4 frags 16x16x32.
// global_load_lds w=16, XOR chunk swizzle.
// XCD-affinity block swizzle: 2504 = 8 x 313 exactly (bijective).
// ---------------------------------------------------------------------------
#define BM 64
#define BN 128
#define BK 64
#define GROWB 313   /* row panels: ceil(20000/64) */

__global__ __launch_bounds__(256) void gemm_mfma(
    const unsigned short* __restrict__ xb,   // [20000][512]
    const unsigned short* __restrict__ wt,   // [1024][512]
    const float* __restrict__ bre, const float* __restrict__ bim,
    unsigned short* __restrict__ y)          // [20000][1024]
{
    __shared__ __align__(16) unsigned short lA[BM * BK];   // 8 KB
    __shared__ __align__(16) unsigned short lB[BN * BK];   // 16 KB

    const int tid  = threadIdx.x;
    const int wave = tid >> 6;
    const int lane = tid & 63;

    // bijective XCD swizzle (nwg = 8*313, r = 0): logical = xcd*313 + slot
    const int bid     = blockIdx.x;
    const int logical = (bid & 7) * GROWB + (bid >> 3);
    const int rowBase = (logical >> 3) * BM;
    const int colBase = (logical & 7) * BN;

    const int wm = (wave >> 1) * 32;
    const int wn = (wave & 1) * 64;

    f32x4 acc[2][4];
#pragma unroll
    for (int i = 0; i < 2; ++i)
#pragma unroll
        for (int j = 0; j < 4; ++j) acc[i][j] = (f32x4){0.f, 0.f, 0.f, 0.f};

    const int srow   = lane >> 3;
    const int schunk = lane & 7;
    const int gchunk = schunk ^ srow;

    const int fm = lane & 15;
    const int kq = lane >> 4;

    for (int k0 = 0; k0 < FDIM; k0 += BK) {
        // stage A: wave stages rows [wave*16, wave*16+16)
#pragma unroll
        for (int i = 0; i < 2; ++i) {
            const int trow = wave * 16 + i * 8;
            int grow = rowBase + trow + srow;
            if (grow > N_NODES - 1) grow = N_NODES - 1;
            const unsigned short* gp = xb + (size_t)grow * FDIM + k0 + gchunk * 8;
            __builtin_amdgcn_global_load_lds(
                (const __attribute__((address_space(1))) void*)gp,
                (__attribute__((address_space(3))) void*)(lA + trow * BK), 16, 0, 0);
        }
        // stage B: wave stages rows [wave*32, wave*32+32)
#pragma unroll
        for (int i = 0; i < 4; ++i) {
            const int trow = wave * 32 + i * 8;
            const int grow = colBase + trow + srow;
            const unsigned short* gp = wt + (size_t)grow * FDIM + k0 + gchunk * 8;
            __builtin_amdgcn_global_load_lds(
                (const __attribute__((address_space(1))) void*)gp,
                (__attribute__((address_space(3))) void*)(lB + trow * BK), 16, 0, 0);
        }
        __syncthreads();

#pragma unroll
        for (int ks = 0; ks < 2; ++ks) {
            bf16x8 af[2], bfr[4];
            const int g = ks * 4 + kq;
#pragma unroll
            for (int mt = 0; mt < 2; ++mt) {
                const int row = wm + mt * 16 + fm;
                af[mt] = *(const bf16x8*)&lA[row * BK + ((g ^ (row & 7)) << 3)];
            }
#pragma unroll
            for (int nt = 0; nt < 4; ++nt) {
                const int row = wn + nt * 16 + fm;
                bfr[nt] = *(const bf16x8*)&lB[row * BK + ((g ^ (row & 7)) << 3)];
            }
#pragma unroll
            for (int mt = 0; mt < 2; ++mt)
#pragma unroll
                for (int nt = 0; nt < 4; ++nt)
                    acc[mt][nt] = __builtin_amdgcn_mfma_f32_16x16x32_bf16(
                        af[mt], bfr[nt], acc[mt][nt], 0, 0, 0);
        }
        __syncthreads();
    }

    const int rquad = lane >> 4;
#pragma unroll
    for (int nt = 0; nt < 4; ++nt) {
        const int col = colBase + wn + nt * 16 + fm;
        const float bias = (col < FDIM) ? bre[col] : bim[col - FDIM];
#pragma unroll
        for (int mt = 0; mt < 2; ++mt) {
            const int row0 = rowBase + wm + mt * 16 + rquad * 4;
#pragma unroll
            for (int r = 0; r < 4; ++r) {
                const int row = row0 + r;
                if (row < N_NODES)
                    y[(size_t)row * 1024 + col] = f2bf(acc[mt][nt][r] + bias);
            }
        }
    }
}

// ---------------------------------------------------------------------------
// K2: evolve + ReLU + fused BN stats (R1-verified structure, 66.4 us).
// Block = 16 nodes (4 waves x 4 nodes). Coeff precomputed. Per-wave register
// partial sums -> LDS cross-wave reduce -> 2048 atomics/block (2.56M total).
// ---------------------------------------------------------------------------
__global__ __launch_bounds__(256) void evolve_stats(
    const unsigned short* __restrict__ y,
    const int* __restrict__ sub_nodes,
    const float* __restrict__ coeff,
    unsigned short* __restrict__ eb,
    float* __restrict__ sums)
{
    __shared__ float lsum[2048];
    const int wave = threadIdx.x >> 6;
    const int lane = threadIdx.x & 63;
    const int f = lane << 3;

    float sR[8] = {0.f}, sR2[8] = {0.f}, sI[8] = {0.f}, sI2[8] = {0.f};

    for (int q = 0; q < 4; ++q) {
        const int n = blockIdx.x * 16 + wave * 4 + q;

        // wave-uniform coefficient load (L1 broadcast)
        const float* cf = coeff + (size_t)n * 12;
        const float4 c0 = *(const float4*)(cf);
        const float4 c1 = *(const float4*)(cf + 4);
        const float4 c2 = *(const float4*)(cf + 8);
        const float rre[SSZ] = {c0.x, c0.y, c0.z, c0.w, c1.x, c1.y};
        const float rim[SSZ] = {c1.z, c1.w, c2.x, c2.y, c2.z, c2.w};

        // gather + complex combine
        float aR[8] = {0.f}, aI[8] = {0.f};
#pragma unroll
        for (int s = 0; s < SSZ; ++s) {
            const int nd = sub_nodes[n * SSZ + s];
            const float cr = rre[s], ci = rim[s];
            const unsigned short* base = y + (size_t)nd * 1024 + f;
            const u16x8 yr8 = *(const u16x8*)base;
            const u16x8 yi8 = *(const u16x8*)(base + FDIM);
#pragma unroll
            for (int j = 0; j < 8; ++j) {
                const float yr = bf2f(yr8[j]);
                const float yi = bf2f(yi8[j]);
                aR[j] = fmaf(cr, yr, fmaf(-ci, yi, aR[j]));
                aI[j] = fmaf(cr, yi, fmaf(ci, yr, aI[j]));
            }
        }
        u16x8 er8, ei8;
#pragma unroll
        for (int j = 0; j < 8; ++j) {
            const unsigned short re = f2bf(fmaxf(aR[j], 0.f));
            const unsigned short im = f2bf(fmaxf(aI[j], 0.f));
            er8[j] = re; ei8[j] = im;
            const float erv = bf2f(re), eiv = bf2f(im);
            sR[j] += erv;  sR2[j] = fmaf(erv, erv, sR2[j]);
            sI[j] += eiv;  sI2[j] = fmaf(eiv, eiv, sI2[j]);
        }
        *(u16x8*)(eb + (size_t)n * 1024 + f) = er8;
        *(u16x8*)(eb + (size_t)n * 1024 + FDIM + f) = ei8;
    }

    // cross-wave reduce in LDS (sequential waves, no atomics)
    if (wave == 0) {
#pragma unroll
        for (int j = 0; j < 8; ++j) {
            lsum[f + j] = sR[j];  lsum[512 + f + j] = sR2[j];
            lsum[1024 + f + j] = sI[j];  lsum[1536 + f + j] = sI2[j];
        }
    }
    for (int w = 1; w < 4; ++w) {
        __syncthreads();
        if (wave == w) {
#pragma unroll
            for (int j = 0; j < 8; ++j) {
                lsum[f + j] += sR[j];  lsum[512 + f + j] += sR2[j];
                lsum[1024 + f + j] += sI[j];  lsum[1536 + f + j] += sI2[j];
            }
        }
    }
    __syncthreads();
#pragma unroll
    for (int i = 0; i < 8; ++i) {
        const int idx = i * 256 + threadIdx.x;
        atomicAdd(&sums[idx], lsum[idx]);
    }
}

// ---------------------------------------------------------------------------
// K3: finalize. Per-thread BN params from sums (register, float4 loads),
// apply + residual, write fp32 out.
// ---------------------------------------------------------------------------
__global__ __launch_bounds__(256) void finalize_kernel(
    const float* __restrict__ x, const unsigned short* __restrict__ eb,
    const float* __restrict__ sums,
    const float* __restrict__ gr, const float* __restrict__ br_,
    const float* __restrict__ gi, const float* __restrict__ bi_,
    float* __restrict__ out)
{
    const int gid = blockIdx.x * 256 + threadIdx.x;    // N*64 threads
    const int n = gid >> 6;
    const int f = (gid & 63) << 3;
    const float invN = 1.0f / (float)N_NODES;

    float scr[8], shr[8], sci[8], shi[8];
#pragma unroll
    for (int h = 0; h < 2; ++h) {
        const int fo = f + h * 4;
        const float4 s1 = *(const float4*)(sums + fo);
        const float4 s2 = *(const float4*)(sums + 512 + fo);
        const float4 s3 = *(const float4*)(sums + 1024 + fo);
        const float4 s4 = *(const float4*)(sums + 1536 + fo);
        const float4 g1 = *(const float4*)(gr + fo);
        const float4 b1 = *(const float4*)(br_ + fo);
        const float4 g2 = *(const float4*)(gi + fo);
        const float4 b2 = *(const float4*)(bi_ + fo);
        const float mu[4] = {s1.x * invN, s1.y * invN, s1.z * invN, s1.w * invN};
        const float q2[4] = {s2.x * invN, s2.y * invN, s2.z * invN, s2.w * invN};
        const float mi[4] = {s3.x * invN, s3.y * invN, s3.z * invN, s3.w * invN};
        const float qi[4] = {s4.x * invN, s4.y * invN, s4.z * invN, s4.w * invN};
        const float gg1[4] = {g1.x, g1.y, g1.z, g1.w};
        const float bb1[4] = {b1.x, b1.y, b1.z, b1.w};
        const float gg2[4] = {g2.x, g2.y, g2.z, g2.w};
        const float bb2[4] = {b2.x, b2.y, b2.z, b2.w};
#pragma unroll
        for (int j = 0; j < 4; ++j) {
            const float vr = fmaf(-mu[j], mu[j], q2[j]);
            const float sc1 = rsqrtf(vr + 1e-5f) * gg1[j];
            scr[h * 4 + j] = sc1;
            shr[h * 4 + j] = fmaf(-mu[j], sc1, bb1[j]);
            const float vi = fmaf(-mi[j], mi[j], qi[j]);
            const float sc2 = rsqrtf(vi + 1e-5f) * gg2[j];
            sci[h * 4 + j] = sc2;
            shi[h * 4 + j] = fmaf(-mi[j], sc2, bb2[j]);
        }
    }

    const u16x8 er8 = *(const u16x8*)(eb + (size_t)n * 1024 + f);
    const u16x8 ei8 = *(const u16x8*)(eb + (size_t)n * 1024 + FDIM + f);
    float orr[8], oii[8];
#pragma unroll
    for (int j = 0; j < 8; ++j) {
        const float xv = x[(size_t)n * FDIM + f + j];
        orr[j] = fmaf(bf2f(er8[j]), scr[j], shr[j]) + xv;
        oii[j] = fmaf(bf2f(ei8[j]), sci[j], shi[j]);
    }
#pragma unroll
    for (int j = 0; j < 8; j += 4) {
        *(float4*)(out + (size_t)n * 1024 + f + j) =
            make_float4(orr[j], orr[j + 1], orr[j + 2], orr[j + 3]);
        *(float4*)(out + (size_t)n * 1024 + FDIM + f + j) =
            make_float4(oii[j], oii[j + 1], oii[j + 2], oii[j + 3]);
    }
}

extern "C" void kernel_launch(void* const* d_in, const int* in_sizes, int n_in,
                              void* d_out, int out_size, void* d_ws, size_t ws_size,
                              hipStream_t stream)
{
    const float* x        = (const float*)d_in[0];
    const int* sub_nodes  = (const int*)d_in[2];
    const int* sub_adj    = (const int*)d_in[3];
    const float* Wre      = (const float*)d_in[4];
    const float* Wim      = (const float*)d_in[5];
    const float* bre      = (const float*)d_in[6];
    const float* bim      = (const float*)d_in[7];
    const float* gr       = (const float*)d_in[8];
    const float* br_      = (const float*)d_in[9];
    const float* gi       = (const float*)d_in[10];
    const float* bi_      = (const float*)d_in[11];
    float* out = (float*)d_out;

    unsigned short* y  = (unsigned short*)d_ws;                     // N*1024 bf16
    unsigned short* eb = y + (size_t)N_NODES * 1024;                // N*1024 bf16
    unsigned short* xb = eb + (size_t)N_NODES * 1024;               // N*512  bf16
    unsigned short* wt = xb + (size_t)N_NODES * FDIM;               // 1024*512 bf16
    float* sums        = (float*)(wt + (size_t)1024 * FDIM);        // 2048
    float* coeff       = sums + 2048;                               // N*12 = 960 KB

    conv_all<<<5513 + 79, 256, 0, stream>>>(x, Wre, Wim, xb, wt, sums, sub_adj, coeff);

    gemm_mfma<<<8 * GROWB, 256, 0, stream>>>(xb, wt, bre, bim, y);

    evolve_stats<<<N_NODES / 16, 256, 0, stream>>>(y, sub_nodes, coeff, eb, sums);

    finalize_kernel<<<(N_NODES * 64) / 256, 256, 0, stream>>>(
        x, eb, sums, gr, br_, gi, bi_, out);
}